// Round 1
// baseline (547.560 us; speedup 1.0000x reference)
//
#include <hip/hip_runtime.h>
#include <hip/hip_bf16.h>

typedef unsigned short u16;
typedef short short8 __attribute__((ext_vector_type(8)));
typedef unsigned short ushort4v __attribute__((ext_vector_type(4)));
typedef float f32x4 __attribute__((ext_vector_type(4)));

#define SEQN 4096
#define HID 2048
#define NH 16
#define NKV 4
#define HD 128
#define QDIM 2048   // NH*HD
#define KVD 512     // NKV*HD

static __device__ __forceinline__ float bf2f(u16 u){
  unsigned x = ((unsigned)u) << 16; float f; __builtin_memcpy(&f, &x, 4); return f;
}
static __device__ __forceinline__ u16 f2bf(float f){
  unsigned x; __builtin_memcpy(&x, &f, 4);
  x += 0x7fffu + ((x >> 16) & 1u);
  return (u16)(x >> 16);
}

// ---------------- fp32 -> bf16 convert ----------------
__global__ __launch_bounds__(256) void cvt_kernel(const float* __restrict__ in, u16* __restrict__ out, int n4){
  int i = blockIdx.x * 256 + threadIdx.x;
  if (i >= n4) return;
  f32x4 v = ((const f32x4*)in)[i];
  ushort4v o;
  o.x = f2bf(v.x); o.y = f2bf(v.y); o.z = f2bf(v.z); o.w = f2bf(v.w);
  ((ushort4v*)out)[i] = o;
}

// ---------------- RoPE (in-place on bf16) ----------------
__global__ __launch_bounds__(256) void rope_kernel(u16* __restrict__ X, int nheads, int total){
  int idx = blockIdx.x * 256 + threadIdx.x;
  if (idx >= total) return;
  int i = idx & 63;          // pair index 0..63
  int rest = idx >> 6;
  int h = rest % nheads;
  int s = rest / nheads;
  // freq = 10000^(-i/64) = exp(-i * ln(10000)/64)
  float freq = expf(-0.14391156831212788f * (float)i);
  float ang = (float)s * freq;
  float c = cosf(ang), sn = sinf(ang);
  u16* p = X + (size_t)s * ((size_t)nheads * HD) + (size_t)h * HD + 2 * i;
  float x1 = bf2f(p[0]), x2 = bf2f(p[1]);
  p[0] = f2bf(x1 * c - x2 * sn);
  p[1] = f2bf(x1 * sn + x2 * c);
}

// ---------------- async global->LDS 16B ----------------
static __device__ __forceinline__ void gload16(const void* g, void* l){
  __builtin_amdgcn_global_load_lds((const __attribute__((address_space(1))) void*)g,
                                   (__attribute__((address_space(3))) void*)l, 16, 0, 0);
}

// ---------------- GEMM: C[M][N] = A[M][K] * B[N][K]^T (bf16 in, bf16/f32 out) ----------------
// m97 structure: 128x128 tile, BK=32, 4 waves (2x2 of 64x64), 16x16x32 MFMA, global_load_lds w=16
template<int F32OUT>
__global__ __launch_bounds__(256) void gemm_kernel(const u16* __restrict__ A, const u16* __restrict__ B,
                                                   void* __restrict__ Cout, int M, int N, int Kd){
  __shared__ alignas(16) u16 As[128 * 32];
  __shared__ alignas(16) u16 Bs[128 * 32];
  const int tid = threadIdx.x;
  const int w = tid >> 6, l = tid & 63;
  const int wr = w >> 1, wc = w & 1;
  const int lc = l & 15, lg = l >> 4;
  const int tm = blockIdx.x * 128, tn = blockIdx.y * 128;

  // staging: chunk c = w*2+i covers LDS rows c*16..c*16+15; lane l -> row +l/4, col (l&3)*8
  const int srow = w * 32 + (l >> 2);
  const int scol = (l & 3) * 8;
  const u16* Ag = A + (size_t)(tm + srow) * Kd + scol;
  const u16* Bg = B + (size_t)(tn + srow) * Kd + scol;
  u16* As0 = As + (w * 2) * 512;
  u16* Bs0 = Bs + (w * 2) * 512;

  f32x4 acc[4][4] = {};

  for (int k0 = 0; k0 < Kd; k0 += 32){
    gload16(Ag + k0,                    As0);
    gload16(Ag + k0 + (size_t)16 * Kd,  As0 + 512);
    gload16(Bg + k0,                    Bs0);
    gload16(Bg + k0 + (size_t)16 * Kd,  Bs0 + 512);
    __syncthreads();
    short8 a[4], b[4];
#pragma unroll
    for (int mi = 0; mi < 4; mi++) a[mi] = *(const short8*)&As[(wr*64 + mi*16 + lc) * 32 + lg*8];
#pragma unroll
    for (int ni = 0; ni < 4; ni++) b[ni] = *(const short8*)&Bs[(wc*64 + ni*16 + lc) * 32 + lg*8];
#pragma unroll
    for (int mi = 0; mi < 4; mi++)
#pragma unroll
      for (int ni = 0; ni < 4; ni++)
        acc[mi][ni] = __builtin_amdgcn_mfma_f32_16x16x32_bf16(a[mi], b[ni], acc[mi][ni], 0, 0, 0);
    __syncthreads();
  }

#pragma unroll
  for (int mi = 0; mi < 4; mi++)
#pragma unroll
    for (int ni = 0; ni < 4; ni++)
#pragma unroll
      for (int r = 0; r < 4; r++){
        int row = tm + wr*64 + mi*16 + lg*4 + r;
        int col = tn + wc*64 + ni*16 + lc;
        float v = acc[mi][ni][r];
        if (F32OUT) ((float*)Cout)[(size_t)row * N + col] = v;
        else        ((u16*)Cout)[(size_t)row * N + col] = f2bf(v);
      }
}

// ---------------- Flash attention (causal, GQA) ----------------
// block: 256 threads = 4 waves; each wave owns 2 row-blocks of 16 q-rows:
//   rows qt*128 + w*16 (m=0) and qt*128 + 64 + w*16 (m=1)  -> balances causal work
// KV tile = 64, K staged natural [64][136], V staged transposed [128][80], P via LDS [16][80]
__global__ __launch_bounds__(256) void attn_kernel(const u16* __restrict__ Q, const u16* __restrict__ K,
                                                   const u16* __restrict__ V, u16* __restrict__ Aout){
  const int qt = blockIdx.x;   // 0..31
  const int h  = blockIdx.y;   // 0..15
  const int kvh = h >> 2;      // GROUPS=4
  const int tid = threadIdx.x;
  const int w = tid >> 6, l = tid & 63;
  const int lc = l & 15, lg = l >> 4;

  __shared__ alignas(16) u16 Ks[64][136];
  __shared__ alignas(16) u16 VT[128][80];
  __shared__ alignas(16) u16 Ps[4][16][80];

  int qbase[2];
  qbase[0] = qt * 128 + w * 16;
  qbase[1] = qt * 128 + 64 + w * 16;

  // Q fragments (A operand): row = l&15, k = (l>>4)*8 + j
  short8 qf[2][4];
#pragma unroll
  for (int m = 0; m < 2; m++){
    const u16* qp = Q + (size_t)(qbase[m] + lc) * QDIM + h * HD + lg * 8;
#pragma unroll
    for (int c = 0; c < 4; c++) qf[m][c] = *(const short8*)(qp + c * 32);
  }

  float Mx[2][4], Lx[2][4];
  f32x4 O[2][8];
#pragma unroll
  for (int m = 0; m < 2; m++)
#pragma unroll
    for (int r = 0; r < 4; r++){ Mx[m][r] = -1e30f; Lx[m][r] = 0.f; }
#pragma unroll
  for (int m = 0; m < 2; m++)
#pragma unroll
    for (int n = 0; n < 8; n++) O[m][n] = (f32x4){0.f, 0.f, 0.f, 0.f};

  const int ntiles = qt * 2 + 2;
  const float scale = 0.08838834764831845f;  // 1/sqrt(128)

  const int krow = tid >> 4;      // 0..15
  const int kch  = tid & 15;
  const int vrow = tid & 63;
  const int vc0  = (tid >> 6) * 8;

  for (int t = 0; t < ntiles; t++){
    const int kv0 = t * 64;
    // ---- stage K tile (natural layout) ----
#pragma unroll
    for (int it = 0; it < 4; it++){
      int r = it * 16 + krow;
      short8 kvec = *(const short8*)(K + (size_t)(kv0 + r) * KVD + kvh * HD + kch * 8);
      *(short8*)&Ks[r][kch * 8] = kvec;
    }
    // ---- stage V tile transposed ----
#pragma unroll
    for (int it = 0; it < 4; it++){
      int cc = vc0 + it * 32;
      short8 vv = *(const short8*)(V + (size_t)(kv0 + vrow) * KVD + kvh * HD + cc);
#pragma unroll
      for (int j = 0; j < 8; j++) VT[cc + j][vrow] = (u16)vv[j];
    }
    __syncthreads();

#pragma unroll
    for (int m = 0; m < 2; m++){
      if (kv0 <= qbase[m] + 15){
        // ---- QK^T: S[16 q][64 kv] ----
        f32x4 sacc[4];
#pragma unroll
        for (int n = 0; n < 4; n++){
          f32x4 s = {0.f, 0.f, 0.f, 0.f};
#pragma unroll
          for (int c = 0; c < 4; c++){
            short8 kf = *(const short8*)&Ks[n * 16 + lc][c * 32 + lg * 8];
            s = __builtin_amdgcn_mfma_f32_16x16x32_bf16(qf[m][c], kf, s, 0, 0, 0);
          }
          sacc[n] = s;
        }
        // ---- scale + causal mask + online softmax ----
        float tmax[4] = {-1e30f, -1e30f, -1e30f, -1e30f};
#pragma unroll
        for (int n = 0; n < 4; n++){
          int kvpos = kv0 + n * 16 + lc;
#pragma unroll
          for (int r = 0; r < 4; r++){
            float sv = sacc[n][r] * scale;
            int qpos = qbase[m] + lg * 4 + r;
            sv = (kvpos > qpos) ? -1e30f : sv;
            sacc[n][r] = sv;
            tmax[r] = fmaxf(tmax[r], sv);
          }
        }
#pragma unroll
        for (int r = 0; r < 4; r++){
          tmax[r] = fmaxf(tmax[r], __shfl_xor(tmax[r], 1));
          tmax[r] = fmaxf(tmax[r], __shfl_xor(tmax[r], 2));
          tmax[r] = fmaxf(tmax[r], __shfl_xor(tmax[r], 4));
          tmax[r] = fmaxf(tmax[r], __shfl_xor(tmax[r], 8));
        }
        float al[4], ps[4];
#pragma unroll
        for (int r = 0; r < 4; r++){
          float nm = fmaxf(Mx[m][r], tmax[r]);
          al[r] = __expf(Mx[m][r] - nm);
          Mx[m][r] = nm;
          float sum = 0.f;
#pragma unroll
          for (int n = 0; n < 4; n++){
            float p = __expf(sacc[n][r] - nm);
            sacc[n][r] = p;
            sum += p;
          }
          ps[r] = sum;
        }
#pragma unroll
        for (int r = 0; r < 4; r++){
          ps[r] += __shfl_xor(ps[r], 1);
          ps[r] += __shfl_xor(ps[r], 2);
          ps[r] += __shfl_xor(ps[r], 4);
          ps[r] += __shfl_xor(ps[r], 8);
          Lx[m][r] = Lx[m][r] * al[r] + ps[r];
        }
#pragma unroll
        for (int n = 0; n < 8; n++)
#pragma unroll
          for (int r = 0; r < 4; r++) O[m][n][r] *= al[r];
        // ---- P -> LDS (bf16, A-fragment order) ----
#pragma unroll
        for (int n = 0; n < 4; n++)
#pragma unroll
          for (int r = 0; r < 4; r++)
            Ps[w][lg * 4 + r][n * 16 + lc] = f2bf(sacc[n][r]);
        // ---- PV: O += P * V ----
#pragma unroll
        for (int kc = 0; kc < 2; kc++){
          short8 pa = *(const short8*)&Ps[w][lc][kc * 32 + lg * 8];
#pragma unroll
          for (int n = 0; n < 8; n++){
            short8 vf = *(const short8*)&VT[n * 16 + lc][kc * 32 + lg * 8];
            O[m][n] = __builtin_amdgcn_mfma_f32_16x16x32_bf16(pa, vf, O[m][n], 0, 0, 0);
          }
        }
      }
    }
    __syncthreads();
  }

  // ---- epilogue: normalize and store bf16 ----
#pragma unroll
  for (int m = 0; m < 2; m++)
#pragma unroll
    for (int n = 0; n < 8; n++)
#pragma unroll
      for (int r = 0; r < 4; r++){
        float v = O[m][n][r] / Lx[m][r];
        Aout[(size_t)(qbase[m] + lg * 4 + r) * QDIM + h * HD + n * 16 + lc] = f2bf(v);
      }
}

extern "C" void kernel_launch(void* const* d_in, const int* in_sizes, int n_in,
                              void* d_out, int out_size, void* d_ws, size_t ws_size,
                              hipStream_t stream){
  const float* x  = (const float*)d_in[0];
  const float* Wq = (const float*)d_in[1];
  const float* Wk = (const float*)d_in[2];
  const float* Wv = (const float*)d_in[3];
  const float* Wo = (const float*)d_in[4];

  char* p = (char*)d_ws;
  u16* xb  = (u16*)p; p += (size_t)SEQN * HID * 2;
  u16* Wqb = (u16*)p; p += (size_t)QDIM * HID * 2;
  u16* Wkb = (u16*)p; p += (size_t)KVD * HID * 2;
  u16* Wvb = (u16*)p; p += (size_t)KVD * HID * 2;
  u16* Wob = (u16*)p; p += (size_t)HID * QDIM * 2;
  u16* Qb  = (u16*)p; p += (size_t)SEQN * QDIM * 2;
  u16* Kb  = (u16*)p; p += (size_t)SEQN * KVD * 2;
  u16* Vb  = (u16*)p; p += (size_t)SEQN * KVD * 2;
  u16* Ab  = (u16*)p; p += (size_t)SEQN * QDIM * 2;

  cvt_kernel<<<(SEQN*HID/4 + 255)/256, 256, 0, stream>>>(x,  xb,  SEQN*HID/4);
  cvt_kernel<<<(QDIM*HID/4 + 255)/256, 256, 0, stream>>>(Wq, Wqb, QDIM*HID/4);
  cvt_kernel<<<(KVD*HID/4 + 255)/256, 256, 0, stream>>>(Wk, Wkb, KVD*HID/4);
  cvt_kernel<<<(KVD*HID/4 + 255)/256, 256, 0, stream>>>(Wv, Wvb, KVD*HID/4);
  cvt_kernel<<<(HID*QDIM/4 + 255)/256, 256, 0, stream>>>(Wo, Wob, HID*QDIM/4);

  gemm_kernel<0><<<dim3(SEQN/128, QDIM/128), 256, 0, stream>>>(xb, Wqb, Qb, SEQN, QDIM, HID);
  gemm_kernel<0><<<dim3(SEQN/128, KVD/128),  256, 0, stream>>>(xb, Wkb, Kb, SEQN, KVD, HID);
  gemm_kernel<0><<<dim3(SEQN/128, KVD/128),  256, 0, stream>>>(xb, Wvb, Vb, SEQN, KVD, HID);

  rope_kernel<<<(SEQN*NH*64)/256,  256, 0, stream>>>(Qb, NH,  SEQN*NH*64);
  rope_kernel<<<(SEQN*NKV*64)/256, 256, 0, stream>>>(Kb, NKV, SEQN*NKV*64);

  attn_kernel<<<dim3(SEQN/128, NH), 256, 0, stream>>>(Qb, Kb, Vb, Ab);

  gemm_kernel<1><<<dim3(SEQN/128, HID/128), 256, 0, stream>>>(Ab, Wob, d_out, SEQN, HID, QDIM);
}

// Round 4
// 534.929 us; speedup vs baseline: 1.0236x; 1.0236x over previous
//
#include <hip/hip_runtime.h>
#include <hip/hip_bf16.h>

typedef unsigned short u16;
typedef unsigned int u32;
typedef short short8 __attribute__((ext_vector_type(8)));
typedef unsigned short ushort4v __attribute__((ext_vector_type(4)));
typedef float f32x4 __attribute__((ext_vector_type(4)));
typedef float f32x16 __attribute__((ext_vector_type(16)));

#define SEQN 4096
#define HID 2048
#define NH 16
#define NKV 4
#define HD 128
#define QDIM 2048   // NH*HD
#define KVD 512     // NKV*HD

static __device__ __forceinline__ float bf2f(u16 u){
  unsigned x = ((unsigned)u) << 16; float f; __builtin_memcpy(&f, &x, 4); return f;
}
static __device__ __forceinline__ u16 f2bf(float f){
  unsigned x; __builtin_memcpy(&x, &f, 4);
  x += 0x7fffu + ((x >> 16) & 1u);
  return (u16)(x >> 16);
}

// ---------------- fp32 -> bf16 convert ----------------
__global__ __launch_bounds__(256) void cvt_kernel(const float* __restrict__ in, u16* __restrict__ out, int n4){
  int i = blockIdx.x * 256 + threadIdx.x;
  if (i >= n4) return;
  f32x4 v = ((const f32x4*)in)[i];
  ushort4v o;
  o.x = f2bf(v.x); o.y = f2bf(v.y); o.z = f2bf(v.z); o.w = f2bf(v.w);
  ((ushort4v*)out)[i] = o;
}

// ---------------- RoPE (in-place on bf16) ----------------
__global__ __launch_bounds__(256) void rope_kernel(u16* __restrict__ X, int nheads, int total){
  int idx = blockIdx.x * 256 + threadIdx.x;
  if (idx >= total) return;
  int i = idx & 63;          // pair index 0..63
  int rest = idx >> 6;
  int h = rest % nheads;
  int s = rest / nheads;
  float freq = expf(-0.14391156831212788f * (float)i);
  float ang = (float)s * freq;
  float c = cosf(ang), sn = sinf(ang);
  u16* p = X + (size_t)s * ((size_t)nheads * HD) + (size_t)h * HD + 2 * i;
  float x1 = bf2f(p[0]), x2 = bf2f(p[1]);
  p[0] = f2bf(x1 * c - x2 * sn);
  p[1] = f2bf(x1 * sn + x2 * c);
}

// ---------------- async global->LDS 16B ----------------
static __device__ __forceinline__ void gload16(const void* g, void* l){
  __builtin_amdgcn_global_load_lds((const __attribute__((address_space(1))) void*)g,
                                   (__attribute__((address_space(3))) void*)l, 16, 0, 0);
}

// ---------------- GEMM: C[M][N] = A[M][K] * B[N][K]^T ----------------
template<int F32OUT>
__global__ __launch_bounds__(256) void gemm_kernel(const u16* __restrict__ A, const u16* __restrict__ B,
                                                   void* __restrict__ Cout, int M, int N, int Kd){
  __shared__ alignas(16) u16 As[128 * 32];
  __shared__ alignas(16) u16 Bs[128 * 32];
  const int tid = threadIdx.x;
  const int w = tid >> 6, l = tid & 63;
  const int wr = w >> 1, wc = w & 1;
  const int lc = l & 15, lg = l >> 4;
  const int tm = blockIdx.x * 128, tn = blockIdx.y * 128;

  const int srow = w * 32 + (l >> 2);
  const int scol = (l & 3) * 8;
  const u16* Ag = A + (size_t)(tm + srow) * Kd + scol;
  const u16* Bg = B + (size_t)(tn + srow) * Kd + scol;
  u16* As0 = As + (w * 2) * 512;
  u16* Bs0 = Bs + (w * 2) * 512;

  f32x4 acc[4][4] = {};

  for (int k0 = 0; k0 < Kd; k0 += 32){
    gload16(Ag + k0,                    As0);
    gload16(Ag + k0 + (size_t)16 * Kd,  As0 + 512);
    gload16(Bg + k0,                    Bs0);
    gload16(Bg + k0 + (size_t)16 * Kd,  Bs0 + 512);
    __syncthreads();
    short8 a[4], b[4];
#pragma unroll
    for (int mi = 0; mi < 4; mi++) a[mi] = *(const short8*)&As[(wr*64 + mi*16 + lc) * 32 + lg*8];
#pragma unroll
    for (int ni = 0; ni < 4; ni++) b[ni] = *(const short8*)&Bs[(wc*64 + ni*16 + lc) * 32 + lg*8];
#pragma unroll
    for (int mi = 0; mi < 4; mi++)
#pragma unroll
      for (int ni = 0; ni < 4; ni++)
        acc[mi][ni] = __builtin_amdgcn_mfma_f32_16x16x32_bf16(a[mi], b[ni], acc[mi][ni], 0, 0, 0);
    __syncthreads();
  }

#pragma unroll
  for (int mi = 0; mi < 4; mi++)
#pragma unroll
    for (int ni = 0; ni < 4; ni++)
#pragma unroll
      for (int r = 0; r < 4; r++){
        int row = tm + wr*64 + mi*16 + lg*4 + r;
        int col = tn + wc*64 + ni*16 + lc;
        float v = acc[mi][ni][r];
        if (F32OUT) ((float*)Cout)[(size_t)row * N + col] = v;
        else        ((u16*)Cout)[(size_t)row * N + col] = f2bf(v);
      }
}

// ---------------- Flash attention (causal, GQA), 32x32 MFMA, swapped ops ----------------
// 4 waves x 32 q-rows each. KV tile 64.
// K in LDS [64][136] natural (r1-verified staging). V transposed into [128][72]
// (8-chunk XOR swizzle per row) via scalar writes. Swapped QK^T -> S^T[kv][q], softmax
// fully per-lane (+1 cross-half shfl). P goes through per-wave LDS [32][72] (same
// swizzle). Swapped PV -> O^T[d][q]. Epilogue transposes via LDS reuse.
__global__ __launch_bounds__(256) void attn_kernel(const u16* __restrict__ Q, const u16* __restrict__ K,
                                                   const u16* __restrict__ V, u16* __restrict__ Aout){
  __shared__ alignas(16) char pool[54272];
  u16 (*Ks)[136] = (u16(*)[136])pool;                  // 64*136*2  = 17408 B
  u16 (*VT)[72]  = (u16(*)[72])(pool + 17408);         // 128*72*2  = 18432 B
  // per-wave P: pool + 35840 + w*4608  ([32][72] u16)

  const int qt  = 31 - blockIdx.x;
  const int h   = blockIdx.y;
  const int kvh = h >> 2;
  const int tid = threadIdx.x;
  const int w = tid >> 6, l = tid & 63;
  const int q5 = l & 31;
  const int hi = l >> 5;
  const int hi4 = hi * 4;
  const int qbase = qt * 128 + w * 32;
  const int qa = qbase + q5;
  const float csc = 0.12751743f;         // (1/sqrt(128)) * log2(e)

  u16 (*Pt)[72] = (u16(*)[72])(pool + 35840 + w * 4608);

  // Q fragments (B operand): col = l&31 = q, k = hi*8 + j
  short8 qf[8];
  {
    const u16* qp = Q + (size_t)(qbase + q5) * QDIM + h * HD + hi * 8;
#pragma unroll
    for (int k0 = 0; k0 < 8; k0++) qf[k0] = *(const short8*)(qp + k0 * 16);
  }

  f32x16 Ov[4] = {};      // O^T: d = nbd*32 + rowmap(r,hi), q = q5
  float Lrow = 0.f;
  float ms = -1e30f;

  const int ntiles = 2 * qt + 2;

  const int krow = tid >> 4;      // 0..15
  const int kch  = tid & 15;
  const int vrow = tid & 63;
  const int vc0  = (tid >> 6) * 8;

  for (int t = 0; t < ntiles; t++){
    const int kv0 = t * 64;

    // ---- stage K tile (natural layout, r1-verified) ----
#pragma unroll
    for (int it = 0; it < 4; it++){
      int r = it * 16 + krow;
      short8 kvec = *(const short8*)(K + (size_t)(kv0 + r) * KVD + kvh * HD + kch * 8);
      *(short8*)&Ks[r][kch * 8] = kvec;
    }
    // ---- stage V transposed, scalar writes, chunk-XOR swizzle ----
#pragma unroll
    for (int it = 0; it < 4; it++){
      int cc = vc0 + it * 32;
      short8 vv = *(const short8*)(V + (size_t)(kv0 + vrow) * KVD + kvh * HD + cc);
#pragma unroll
      for (int j = 0; j < 8; j++){
        int d = cc + j;
        int chunk = (vrow >> 3) ^ ((d >> 3) & 3);
        VT[d][chunk * 8 + (vrow & 7)] = (u16)vv[j];
      }
    }
    __syncthreads();

    if (kv0 <= qbase + 31){
      // ---- QK^T swapped: S^T[kv][q] ----
      f32x16 Sv[2] = {};
#pragma unroll
      for (int k0 = 0; k0 < 8; k0++){
#pragma unroll
        for (int nb = 0; nb < 2; nb++){
          int kvr = nb * 32 + q5;
          short8 kf = *(const short8*)&Ks[kvr][(k0 * 2 + hi) * 8];
          Sv[nb] = __builtin_amdgcn_mfma_f32_32x32x16_bf16(kf, qf[k0], Sv[nb], 0, 0, 0);
        }
      }
      // ---- causal mask (raw scores) ----
      if (kv0 + 63 > qbase){
#pragma unroll
        for (int nb = 0; nb < 2; nb++)
#pragma unroll
          for (int r = 0; r < 16; r++){
            int kva = kv0 + nb * 32 + (r & 3) + 8 * (r >> 2) + hi4;
            if (kva > qa) Sv[nb][r] = -1e30f;
          }
      }
      // ---- online softmax, scaled-log2 domain, defer-max THR=8 ----
      float tm = -3e38f;
#pragma unroll
      for (int nb = 0; nb < 2; nb++)
#pragma unroll
        for (int r = 0; r < 16; r++) tm = fmaxf(tm, Sv[nb][r]);
      tm = fmaxf(tm, __shfl_xor(tm, 32));
      float tms = tm * csc;
      if (!__all(tms - ms <= 8.f)){
        float nms = fmaxf(ms, tms);
        float al = __builtin_amdgcn_exp2f(ms - nms);
        ms = nms;
        Lrow *= al;
#pragma unroll
        for (int nb = 0; nb < 4; nb++)
#pragma unroll
          for (int r = 0; r < 16; r++) Ov[nb][r] *= al;
      }
      float ts = 0.f;
#pragma unroll
      for (int nb = 0; nb < 2; nb++)
#pragma unroll
        for (int r = 0; r < 16; r++){
          float p = __builtin_amdgcn_exp2f(__builtin_fmaf(Sv[nb][r], csc, -ms));
          Sv[nb][r] = p;
          ts += p;
        }
      ts += __shfl_xor(ts, 32);
      Lrow += ts;
      // ---- P -> per-wave LDS (bf16 pairs, swizzled like VT) ----
#pragma unroll
      for (int nb = 0; nb < 2; nb++)
#pragma unroll
        for (int r = 0; r < 16; r += 2){
          int kvp = nb * 32 + (r & 3) + 8 * (r >> 2) + hi4;   // even
          u32 pv = (u32)f2bf(Sv[nb][r]) | ((u32)f2bf(Sv[nb][r + 1]) << 16);
          int chunk = (kvp >> 3) ^ ((q5 >> 3) & 3);
          *(u32*)((char*)Pt + q5 * 144 + chunk * 16 + (kvp & 7) * 2) = pv;
        }
      // ---- PV swapped: O^T[d][q] += V^T * P^T ----
#pragma unroll
      for (int kc = 0; kc < 4; kc++){
        short8 pf = *(const short8*)((const char*)Pt + q5 * 144 + (((kc * 2 + hi) ^ ((q5 >> 3) & 3)) * 16));
#pragma unroll
        for (int nbd = 0; nbd < 4; nbd++){
          int drow = nbd * 32 + q5;
          short8 vf = *(const short8*)&VT[drow][((kc * 2 + hi) ^ ((drow >> 3) & 3)) * 8];
          Ov[nbd] = __builtin_amdgcn_mfma_f32_32x32x16_bf16(vf, pf, Ov[nbd], 0, 0, 0);
        }
      }
    }
    __syncthreads();
  }

  // ---- epilogue: normalize, transpose via per-wave LDS reuse, coalesced store ----
  u16* Ew = (u16*)(pool + w * 8704);     // [32 q][136 d] u16
  float rl = 1.f / Lrow;
#pragma unroll
  for (int nbd = 0; nbd < 4; nbd++)
#pragma unroll
    for (int r = 0; r < 16; r += 2){
      int d = nbd * 32 + (r & 3) + 8 * (r >> 2) + hi4;       // even
      u32 wpk = (u32)f2bf(Ov[nbd][r] * rl) | ((u32)f2bf(Ov[nbd][r + 1] * rl) << 16);
      *(u32*)((char*)Ew + q5 * 272 + d * 2) = wpk;
    }
#pragma unroll
  for (int pass = 0; pass < 8; pass++){
    int q2 = pass * 4 + (l >> 4);
    short8 ov = *(const short8*)((char*)Ew + q2 * 272 + (l & 15) * 16);
    *(short8*)(Aout + (size_t)(qbase + q2) * QDIM + h * HD + (l & 15) * 8) = ov;
  }
}

extern "C" void kernel_launch(void* const* d_in, const int* in_sizes, int n_in,
                              void* d_out, int out_size, void* d_ws, size_t ws_size,
                              hipStream_t stream){
  const float* x  = (const float*)d_in[0];
  const float* Wq = (const float*)d_in[1];
  const float* Wk = (const float*)d_in[2];
  const float* Wv = (const float*)d_in[3];
  const float* Wo = (const float*)d_in[4];

  char* p = (char*)d_ws;
  u16* xb  = (u16*)p; p += (size_t)SEQN * HID * 2;
  u16* Wqb = (u16*)p; p += (size_t)QDIM * HID * 2;
  u16* Wkb = (u16*)p; p += (size_t)KVD * HID * 2;
  u16* Wvb = (u16*)p; p += (size_t)KVD * HID * 2;
  u16* Wob = (u16*)p; p += (size_t)HID * QDIM * 2;
  u16* Qb  = (u16*)p; p += (size_t)SEQN * QDIM * 2;
  u16* Kb  = (u16*)p; p += (size_t)SEQN * KVD * 2;
  u16* Vb  = (u16*)p; p += (size_t)SEQN * KVD * 2;
  u16* Ab  = (u16*)p; p += (size_t)SEQN * QDIM * 2;

  cvt_kernel<<<(SEQN*HID/4 + 255)/256, 256, 0, stream>>>(x,  xb,  SEQN*HID/4);
  cvt_kernel<<<(QDIM*HID/4 + 255)/256, 256, 0, stream>>>(Wq, Wqb, QDIM*HID/4);
  cvt_kernel<<<(KVD*HID/4 + 255)/256, 256, 0, stream>>>(Wk, Wkb, KVD*HID/4);
  cvt_kernel<<<(KVD*HID/4 + 255)/256, 256, 0, stream>>>(Wv, Wvb, KVD*HID/4);
  cvt_kernel<<<(HID*QDIM/4 + 255)/256, 256, 0, stream>>>(Wo, Wob, HID*QDIM/4);

  gemm_kernel<0><<<dim3(SEQN/128, QDIM/128), 256, 0, stream>>>(xb, Wqb, Qb, SEQN, QDIM, HID);
  gemm_kernel<0><<<dim3(SEQN/128, KVD/128),  256, 0, stream>>>(xb, Wkb, Kb, SEQN, KVD, HID);
  gemm_kernel<0><<<dim3(SEQN/128, KVD/128),  256, 0, stream>>>(xb, Wvb, Vb, SEQN, KVD, HID);

  rope_kernel<<<(SEQN*NH*64)/256,  256, 0, stream>>>(Qb, NH,  SEQN*NH*64);
  rope_kernel<<<(SEQN*NKV*64)/256, 256, 0, stream>>>(Kb, NKV, SEQN*NKV*64);

  attn_kernel<<<dim3(32, NH), 256, 0, stream>>>(Qb, Kb, Vb, Ab);

  gemm_kernel<1><<<dim3(SEQN/128, HID/128), 256, 0, stream>>>(Ab, Wob, d_out, SEQN, HID, QDIM);
}

// Round 5
// 376.712 us; speedup vs baseline: 1.4535x; 1.4200x over previous
//
#include <hip/hip_runtime.h>
#include <hip/hip_bf16.h>

typedef unsigned short u16;
typedef unsigned int u32;
typedef short short8 __attribute__((ext_vector_type(8)));
typedef unsigned short ushort4v __attribute__((ext_vector_type(4)));
typedef float f32x4 __attribute__((ext_vector_type(4)));
typedef float f32x16 __attribute__((ext_vector_type(16)));

#define SEQN 4096
#define HID 2048
#define NH 16
#define NKV 4
#define HD 128
#define QDIM 2048   // NH*HD
#define KVD 512     // NKV*HD

static __device__ __forceinline__ float bf2f(u16 u){
  unsigned x = ((unsigned)u) << 16; float f; __builtin_memcpy(&f, &x, 4); return f;
}
static __device__ __forceinline__ u16 f2bf(float f){
  unsigned x; __builtin_memcpy(&x, &f, 4);
  x += 0x7fffu + ((x >> 16) & 1u);
  return (u16)(x >> 16);
}

// ---------------- fp32 -> bf16 convert ----------------
__global__ __launch_bounds__(256) void cvt_kernel(const float* __restrict__ in, u16* __restrict__ out, int n4){
  int i = blockIdx.x * 256 + threadIdx.x;
  if (i >= n4) return;
  f32x4 v = ((const f32x4*)in)[i];
  ushort4v o;
  o.x = f2bf(v.x); o.y = f2bf(v.y); o.z = f2bf(v.z); o.w = f2bf(v.w);
  ((ushort4v*)out)[i] = o;
}

// ---------------- RoPE (in-place on bf16) ----------------
__global__ __launch_bounds__(256) void rope_kernel(u16* __restrict__ X, int nheads, int total){
  int idx = blockIdx.x * 256 + threadIdx.x;
  if (idx >= total) return;
  int i = idx & 63;          // pair index 0..63
  int rest = idx >> 6;
  int h = rest % nheads;
  int s = rest / nheads;
  float freq = expf(-0.14391156831212788f * (float)i);
  float ang = (float)s * freq;
  float c = cosf(ang), sn = sinf(ang);
  u16* p = X + (size_t)s * ((size_t)nheads * HD) + (size_t)h * HD + 2 * i;
  float x1 = bf2f(p[0]), x2 = bf2f(p[1]);
  p[0] = f2bf(x1 * c - x2 * sn);
  p[1] = f2bf(x1 * sn + x2 * c);
}

// ---------------- async global->LDS 16B ----------------
static __device__ __forceinline__ void gload16(const void* g, void* l){
  __builtin_amdgcn_global_load_lds((const __attribute__((address_space(1))) void*)g,
                                   (__attribute__((address_space(3))) void*)l, 16, 0, 0);
}

// ---------------- GEMM: C[M][N] = A[M][K] * B[N][K]^T ----------------
template<int F32OUT>
__global__ __launch_bounds__(256) void gemm_kernel(const u16* __restrict__ A, const u16* __restrict__ B,
                                                   void* __restrict__ Cout, int M, int N, int Kd){
  __shared__ alignas(16) u16 As[128 * 32];
  __shared__ alignas(16) u16 Bs[128 * 32];
  const int tid = threadIdx.x;
  const int w = tid >> 6, l = tid & 63;
  const int wr = w >> 1, wc = w & 1;
  const int lc = l & 15, lg = l >> 4;
  const int tm = blockIdx.x * 128, tn = blockIdx.y * 128;

  const int srow = w * 32 + (l >> 2);
  const int scol = (l & 3) * 8;
  const u16* Ag = A + (size_t)(tm + srow) * Kd + scol;
  const u16* Bg = B + (size_t)(tn + srow) * Kd + scol;
  u16* As0 = As + (w * 2) * 512;
  u16* Bs0 = Bs + (w * 2) * 512;

  f32x4 acc[4][4] = {};

  for (int k0 = 0; k0 < Kd; k0 += 32){
    gload16(Ag + k0,                    As0);
    gload16(Ag + k0 + (size_t)16 * Kd,  As0 + 512);
    gload16(Bg + k0,                    Bs0);
    gload16(Bg + k0 + (size_t)16 * Kd,  Bs0 + 512);
    __syncthreads();
    short8 a[4], b[4];
#pragma unroll
    for (int mi = 0; mi < 4; mi++) a[mi] = *(const short8*)&As[(wr*64 + mi*16 + lc) * 32 + lg*8];
#pragma unroll
    for (int ni = 0; ni < 4; ni++) b[ni] = *(const short8*)&Bs[(wc*64 + ni*16 + lc) * 32 + lg*8];
#pragma unroll
    for (int mi = 0; mi < 4; mi++)
#pragma unroll
      for (int ni = 0; ni < 4; ni++)
        acc[mi][ni] = __builtin_amdgcn_mfma_f32_16x16x32_bf16(a[mi], b[ni], acc[mi][ni], 0, 0, 0);
    __syncthreads();
  }

#pragma unroll
  for (int mi = 0; mi < 4; mi++)
#pragma unroll
    for (int ni = 0; ni < 4; ni++)
#pragma unroll
      for (int r = 0; r < 4; r++){
        int row = tm + wr*64 + mi*16 + lg*4 + r;
        int col = tn + wc*64 + ni*16 + lc;
        float v = acc[mi][ni][r];
        if (F32OUT) ((float*)Cout)[(size_t)row * N + col] = v;
        else        ((u16*)Cout)[(size_t)row * N + col] = f2bf(v);
      }
}

// ---------------- Flash attention (causal, GQA), 32x32 MFMA, swapped ops ----------------
// Causal-balanced: block x in [0,16) processes q-super-blocks qt=x AND qt=31-x
// sequentially -> every block does exactly 66 KV tiles (uniform). Grid 16x16 = 256
// blocks = 1/CU. 4 waves x 32 q-rows. KV tile 64, reg-staged with T14 prefetch
// (tile t+1 global loads issue before tile t compute).
// K in LDS [64][136] natural. V transposed into [128][72] (8-chunk XOR swizzle).
// Swapped QK^T -> S^T[kv][q], softmax fully per-lane (+1 cross-half shfl).
// P via per-wave LDS [32][72]. Swapped PV -> O^T[d][q]. Epilogue transposes via LDS.
__global__ __launch_bounds__(256) void attn_kernel(const u16* __restrict__ Q, const u16* __restrict__ K,
                                                   const u16* __restrict__ V, u16* __restrict__ Aout){
  __shared__ alignas(16) char pool[54272];
  u16 (*Ks)[136] = (u16(*)[136])pool;                  // 64*136*2  = 17408 B
  u16 (*VT)[72]  = (u16(*)[72])(pool + 17408);         // 128*72*2  = 18432 B
  // per-wave P: pool + 35840 + w*4608  ([32][72] u16)

  const int pr  = blockIdx.x;            // 0..15
  const int h   = blockIdx.y;
  const int kvh = h >> 2;
  const int tid = threadIdx.x;
  const int w = tid >> 6, l = tid & 63;
  const int q5 = l & 31;
  const int hi = l >> 5;
  const int hi4 = hi * 4;
  const float csc = 0.12751743f;         // (1/sqrt(128)) * log2(e)

  u16 (*Pt)[72] = (u16(*)[72])(pool + 35840 + w * 4608);

  const int krow = tid >> 4;      // 0..15
  const int kch  = tid & 15;
  const int vrow = tid & 63;
  const int vc0  = (tid >> 6) * 8;

  for (int ph = 0; ph < 2; ph++){
    const int qt    = ph ? (31 - pr) : pr;
    const int qbase = qt * 128 + w * 32;
    const int qa    = qbase + q5;
    const int ntiles = 2 * qt + 2;

    // Q fragments (B operand): col = l&31 = q, k = hi*8 + j
    short8 qf[8];
    {
      const u16* qp = Q + (size_t)(qbase + q5) * QDIM + h * HD + hi * 8;
#pragma unroll
      for (int k0 = 0; k0 < 8; k0++) qf[k0] = *(const short8*)(qp + k0 * 16);
    }

    f32x16 Ov[4] = {};      // O^T: d = nbd*32 + rowmap(r,hi), q = q5
    float Lrow = 0.f;
    float ms = -1e30f;

    // ---- prefetch tile 0 into regs ----
    short8 kr[4], vr[4];
#pragma unroll
    for (int it = 0; it < 4; it++)
      kr[it] = *(const short8*)(K + (size_t)(it * 16 + krow) * KVD + kvh * HD + kch * 8);
#pragma unroll
    for (int it = 0; it < 4; it++)
      vr[it] = *(const short8*)(V + (size_t)vrow * KVD + kvh * HD + vc0 + it * 32);

    for (int t = 0; t < ntiles; t++){
      const int kv0 = t * 64;

      __syncthreads();    // previous tile's compute (and prev phase epilogue) done

      // ---- write staged K regs -> LDS (natural layout) ----
#pragma unroll
      for (int it = 0; it < 4; it++)
        *(short8*)&Ks[it * 16 + krow][kch * 8] = kr[it];
      // ---- write staged V regs -> LDS transposed (scalar, chunk-XOR swizzle) ----
#pragma unroll
      for (int it = 0; it < 4; it++){
        int cc = vc0 + it * 32;
#pragma unroll
        for (int j = 0; j < 8; j++){
          int d = cc + j;
          int chunk = (vrow >> 3) ^ ((d >> 3) & 3);
          VT[d][chunk * 8 + (vrow & 7)] = (u16)vr[it][j];
        }
      }
      // ---- issue next tile's global loads (hide latency under compute) ----
      if (t + 1 < ntiles){
        const int nkv = kv0 + 64;
#pragma unroll
        for (int it = 0; it < 4; it++)
          kr[it] = *(const short8*)(K + (size_t)(nkv + it * 16 + krow) * KVD + kvh * HD + kch * 8);
#pragma unroll
        for (int it = 0; it < 4; it++)
          vr[it] = *(const short8*)(V + (size_t)(nkv + vrow) * KVD + kvh * HD + vc0 + it * 32);
      }
      __syncthreads();    // LDS tile ready

      if (kv0 <= qbase + 31){
        // ---- QK^T swapped: S^T[kv][q] ----
        f32x16 Sv[2] = {};
#pragma unroll
        for (int k0 = 0; k0 < 8; k0++){
#pragma unroll
          for (int nb = 0; nb < 2; nb++){
            int kvr = nb * 32 + q5;
            short8 kf = *(const short8*)&Ks[kvr][(k0 * 2 + hi) * 8];
            Sv[nb] = __builtin_amdgcn_mfma_f32_32x32x16_bf16(kf, qf[k0], Sv[nb], 0, 0, 0);
          }
        }
        // ---- causal mask (raw scores) ----
        if (kv0 + 63 > qbase){
#pragma unroll
          for (int nb = 0; nb < 2; nb++)
#pragma unroll
            for (int r = 0; r < 16; r++){
              int kva = kv0 + nb * 32 + (r & 3) + 8 * (r >> 2) + hi4;
              if (kva > qa) Sv[nb][r] = -1e30f;
            }
        }
        // ---- online softmax, scaled-log2 domain, defer-max THR=8 ----
        float tm = -3e38f;
#pragma unroll
        for (int nb = 0; nb < 2; nb++)
#pragma unroll
          for (int r = 0; r < 16; r++) tm = fmaxf(tm, Sv[nb][r]);
        tm = fmaxf(tm, __shfl_xor(tm, 32));
        float tms = tm * csc;
        if (!__all(tms - ms <= 8.f)){
          float nms = fmaxf(ms, tms);
          float al = __builtin_amdgcn_exp2f(ms - nms);
          ms = nms;
          Lrow *= al;
#pragma unroll
          for (int nb = 0; nb < 4; nb++)
#pragma unroll
            for (int r = 0; r < 16; r++) Ov[nb][r] *= al;
        }
        float ts = 0.f;
#pragma unroll
        for (int nb = 0; nb < 2; nb++)
#pragma unroll
          for (int r = 0; r < 16; r++){
            float p = __builtin_amdgcn_exp2f(__builtin_fmaf(Sv[nb][r], csc, -ms));
            Sv[nb][r] = p;
            ts += p;
          }
        ts += __shfl_xor(ts, 32);
        Lrow += ts;
        // ---- P -> per-wave LDS (bf16 pairs, swizzled like VT) ----
#pragma unroll
        for (int nb = 0; nb < 2; nb++)
#pragma unroll
          for (int r = 0; r < 16; r += 2){
            int kvp = nb * 32 + (r & 3) + 8 * (r >> 2) + hi4;   // even
            u32 pv = (u32)f2bf(Sv[nb][r]) | ((u32)f2bf(Sv[nb][r + 1]) << 16);
            int chunk = (kvp >> 3) ^ ((q5 >> 3) & 3);
            *(u32*)((char*)Pt + q5 * 144 + chunk * 16 + (kvp & 7) * 2) = pv;
          }
        // ---- PV swapped: O^T[d][q] += V^T * P^T ----
#pragma unroll
        for (int kc = 0; kc < 4; kc++){
          short8 pf = *(const short8*)((const char*)Pt + q5 * 144 + (((kc * 2 + hi) ^ ((q5 >> 3) & 3)) * 16));
#pragma unroll
          for (int nbd = 0; nbd < 4; nbd++){
            int drow = nbd * 32 + q5;
            short8 vf = *(const short8*)&VT[drow][((kc * 2 + hi) ^ ((drow >> 3) & 3)) * 8];
            Ov[nbd] = __builtin_amdgcn_mfma_f32_32x32x16_bf16(vf, pf, Ov[nbd], 0, 0, 0);
          }
        }
      }
    }

    __syncthreads();    // all waves done computing before epilogue overwrites pool

    // ---- epilogue: normalize, transpose via per-wave LDS reuse, coalesced store ----
    u16* Ew = (u16*)(pool + w * 8704);     // [32 q][136 d] u16
    float rl = 1.f / Lrow;
#pragma unroll
    for (int nbd = 0; nbd < 4; nbd++)
#pragma unroll
      for (int r = 0; r < 16; r += 2){
        int d = nbd * 32 + (r & 3) + 8 * (r >> 2) + hi4;       // even
        u32 wpk = (u32)f2bf(Ov[nbd][r] * rl) | ((u32)f2bf(Ov[nbd][r + 1] * rl) << 16);
        *(u32*)((char*)Ew + q5 * 272 + d * 2) = wpk;
      }
#pragma unroll
    for (int pass = 0; pass < 8; pass++){
      int q2 = pass * 4 + (l >> 4);
      short8 ov = *(const short8*)((char*)Ew + q2 * 272 + (l & 15) * 16);
      *(short8*)(Aout + (size_t)(qbase + q2) * QDIM + h * HD + (l & 15) * 8) = ov;
    }
    // next phase's first in-loop barrier protects Ew reads (all waves rejoin there)
  }
}

extern "C" void kernel_launch(void* const* d_in, const int* in_sizes, int n_in,
                              void* d_out, int out_size, void* d_ws, size_t ws_size,
                              hipStream_t stream){
  const float* x  = (const float*)d_in[0];
  const float* Wq = (const float*)d_in[1];
  const float* Wk = (const float*)d_in[2];
  const float* Wv = (const float*)d_in[3];
  const float* Wo = (const float*)d_in[4];

  char* p = (char*)d_ws;
  u16* xb  = (u16*)p; p += (size_t)SEQN * HID * 2;
  u16* Wqb = (u16*)p; p += (size_t)QDIM * HID * 2;
  u16* Wkb = (u16*)p; p += (size_t)KVD * HID * 2;
  u16* Wvb = (u16*)p; p += (size_t)KVD * HID * 2;
  u16* Wob = (u16*)p; p += (size_t)HID * QDIM * 2;
  u16* Qb  = (u16*)p; p += (size_t)SEQN * QDIM * 2;
  u16* Kb  = (u16*)p; p += (size_t)SEQN * KVD * 2;
  u16* Vb  = (u16*)p; p += (size_t)SEQN * KVD * 2;
  u16* Ab  = (u16*)p; p += (size_t)SEQN * QDIM * 2;

  cvt_kernel<<<(SEQN*HID/4 + 255)/256, 256, 0, stream>>>(x,  xb,  SEQN*HID/4);
  cvt_kernel<<<(QDIM*HID/4 + 255)/256, 256, 0, stream>>>(Wq, Wqb, QDIM*HID/4);
  cvt_kernel<<<(KVD*HID/4 + 255)/256, 256, 0, stream>>>(Wk, Wkb, KVD*HID/4);
  cvt_kernel<<<(KVD*HID/4 + 255)/256, 256, 0, stream>>>(Wv, Wvb, KVD*HID/4);
  cvt_kernel<<<(HID*QDIM/4 + 255)/256, 256, 0, stream>>>(Wo, Wob, HID*QDIM/4);

  gemm_kernel<0><<<dim3(SEQN/128, QDIM/128), 256, 0, stream>>>(xb, Wqb, Qb, SEQN, QDIM, HID);
  gemm_kernel<0><<<dim3(SEQN/128, KVD/128),  256, 0, stream>>>(xb, Wkb, Kb, SEQN, KVD, HID);
  gemm_kernel<0><<<dim3(SEQN/128, KVD/128),  256, 0, stream>>>(xb, Wvb, Vb, SEQN, KVD, HID);

  rope_kernel<<<(SEQN*NH*64)/256,  256, 0, stream>>>(Qb, NH,  SEQN*NH*64);
  rope_kernel<<<(SEQN*NKV*64)/256, 256, 0, stream>>>(Kb, NKV, SEQN*NKV*64);

  attn_kernel<<<dim3(16, NH), 256, 0, stream>>>(Qb, Kb, Vb, Ab);

  gemm_kernel<1><<<dim3(SEQN/128, HID/128), 256, 0, stream>>>(Ab, Wob, d_out, SEQN, HID, QDIM);
}